// Round 9
// baseline (576.818 us; speedup 1.0000x reference)
//
#include <hip/hip_runtime.h>
#include <math.h>

#define BB 32
#define NN 16384
#define GG 128
#define KK 64
#define HH 128
#define DD 384
#define LN_EPS 1e-5f
#define NBUCK 2048
#define CANDCAP 1024

// round-to-nearest sum of 3 squares, matching jnp.sum(x**2, -1) order, no FMA contraction
__device__ __forceinline__ float sq3(float x, float y, float z) {
    return __fadd_rn(__fadd_rn(__fmul_rn(x, x), __fmul_rn(y, y)), __fmul_rn(z, z));
}

// order-preserving uint key of dist2, same formula/rounding as reference
__device__ __forceinline__ unsigned distkey(float px, float py, float pz, float4 c4) {
    float p2 = sq3(px, py, pz);
    float dot = __fadd_rn(__fadd_rn(__fmul_rn(c4.x, px), __fmul_rn(c4.y, py)),
                          __fmul_rn(c4.z, pz));
    float d = __fsub_rn(__fadd_rn(c4.w, p2), __fmul_rn(2.0f, dot));
    unsigned u = __float_as_uint(d);
    return u ^ ((u & 0x80000000u) ? 0xFFFFFFFFu : 0x80000000u);
}

// same key, but p2 precomputed (bit-identical: p4.w was produced by the same sq3)
__device__ __forceinline__ unsigned distkey4(float4 p4v, float4 c4) {
    float dot = __fadd_rn(__fadd_rn(__fmul_rn(c4.x, p4v.x), __fmul_rn(c4.y, p4v.y)),
                          __fmul_rn(c4.z, p4v.z));
    float d = __fsub_rn(__fadd_rn(c4.w, p4v.w), __fmul_rn(2.0f, dot));
    unsigned u = __float_as_uint(d);
    return u ^ ((u & 0x80000000u) ? 0xFFFFFFFFu : 0x80000000u);
}

// ---------------- prep: transpose w2 [128,384] -> w2t [384,128] ----------------
__global__ void prep_kernel(const float* __restrict__ w2, float* __restrict__ w2t) {
    int i = blockIdx.x * 256 + threadIdx.x;  // over DD*HH = 49152
    if (i < HH * DD) {
        int f = i >> 7;    // 0..383
        int k = i & 127;   // 0..127
        w2t[i] = w2[k * DD + f];
    }
}

// ---------------- prep2: pad points to (x,y,z,p2) float4 -- p2 is centroid-invariant
// and was being recomputed 256x per batch inside group passes. sq3 rounding identical.
__global__ void prep_pts4(const float* __restrict__ pts, float4* __restrict__ pts4) {
    int q = blockIdx.x * 256 + threadIdx.x;  // quad id over BB*NN/4 = 131072
    const float4* p4 = (const float4*)pts;
    float4 A = p4[3 * q], B = p4[3 * q + 1], C = p4[3 * q + 2];
    pts4[4 * q + 0] = make_float4(A.x, A.y, A.z, sq3(A.x, A.y, A.z));
    pts4[4 * q + 1] = make_float4(A.w, B.x, B.y, sq3(A.w, B.x, B.y));
    pts4[4 * q + 2] = make_float4(B.z, B.w, C.x, sq3(B.z, B.w, C.x));
    pts4[4 * q + 3] = make_float4(C.y, C.z, C.w, sq3(C.y, C.z, C.w));
}

// ---------------- FPS: one block per batch, 512 threads, 32 pts/thread ----------------
// Round-0 code, proven 275us plateau (rounds 1-7: every structural alternative lost).
__global__ __launch_bounds__(512, 2) void fps_kernel(const float* __restrict__ pts,
                                                     float* __restrict__ cent_out,
                                                     float4* __restrict__ cent_pad) {
    const int b = blockIdx.x;
    const int tid = threadIdx.x;
    const float* p = pts + (size_t)b * NN * 3;
    const float4* p4 = (const float4*)p;

    float x[32], y[32], z[32], dist[32];
#pragma unroll
    for (int j = 0; j < 8; j++) {
        int q = j * 512 + tid;
        float4 A = p4[3 * q], B = p4[3 * q + 1], C = p4[3 * q + 2];
        x[j * 4 + 0] = A.x; y[j * 4 + 0] = A.y; z[j * 4 + 0] = A.z;
        x[j * 4 + 1] = A.w; y[j * 4 + 1] = B.x; z[j * 4 + 1] = B.y;
        x[j * 4 + 2] = B.z; y[j * 4 + 2] = B.w; z[j * 4 + 2] = C.x;
        x[j * 4 + 3] = C.y; y[j * 4 + 3] = C.z; z[j * 4 + 3] = C.w;
#pragma unroll
        for (int t = 0; t < 4; t++) dist[j * 4 + t] = INFINITY;
    }

    __shared__ unsigned long long slot[GG];
    for (int i = tid; i < GG; i += 512) slot[i] = 0ull;
    __syncthreads();

    float cx = p[0], cy = p[1], cz = p[2];

    for (int it = 0; it < GG; it++) {
        if (tid == 0) {
            float* co = cent_out + ((size_t)b * GG + it) * 3;
            co[0] = cx; co[1] = cy; co[2] = cz;
            cent_pad[b * GG + it] = make_float4(cx, cy, cz, sq3(cx, cy, cz));
        }
        if (it == GG - 1) break;

        float bv0 = -INFINITY, bv1 = -INFINITY, bv2 = -INFINITY, bv3 = -INFINITY;
        int bi0 = 0, bi1 = 0, bi2 = 0, bi3 = 0;
#pragma unroll
        for (int j = 0; j < 8; j++) {
            int nb = 4 * (j * 512 + tid);
#pragma unroll
            for (int t = 0; t < 4; t++) {
                int r = j * 4 + t;
                float dx = __fsub_rn(x[r], cx);
                float dy = __fsub_rn(y[r], cy);
                float dz = __fsub_rn(z[r], cz);
                float d = sq3(dx, dy, dz);
                float dj = fminf(dist[r], d);
                dist[r] = dj;
                int n = nb + t;
                switch (t) {
                    case 0: if (dj > bv0) { bv0 = dj; bi0 = n; } break;
                    case 1: if (dj > bv1) { bv1 = dj; bi1 = n; } break;
                    case 2: if (dj > bv2) { bv2 = dj; bi2 = n; } break;
                    case 3: if (dj > bv3) { bv3 = dj; bi3 = n; } break;
                }
            }
        }
        float fv = bv0; int fi = bi0;
        if (bv1 > fv || (bv1 == fv && bi1 < fi)) { fv = bv1; fi = bi1; }
        if (bv2 > fv || (bv2 == fv && bi2 < fi)) { fv = bv2; fi = bi2; }
        if (bv3 > fv || (bv3 == fv && bi3 < fi)) { fv = bv3; fi = bi3; }
#pragma unroll
        for (int off = 32; off >= 1; off >>= 1) {
            float ov = __shfl_down(fv, off);
            int oi = __shfl_down(fi, off);
            if (ov > fv || (ov == fv && oi < fi)) { fv = ov; fi = oi; }
        }
        if ((tid & 63) == 0) {
            unsigned long long packed =
                ((unsigned long long)__float_as_uint(fv) << 32) |
                (unsigned)(0xFFFFFFFFu - (unsigned)fi);
            atomicMax(&slot[it], packed);
        }
        __syncthreads();
        unsigned long long w = slot[it];
        int idx = (int)(0xFFFFFFFFu - (unsigned)w);
        const float* wp = p + (size_t)idx * 3;
        cx = wp[0]; cy = wp[1]; cz = wp[2];
    }
}

// ================== shared group-kernel body (templated on point source) =============
// SRC=1: padded float4 (x,y,z,p2) -- cheaper keys (9 vs 16 VALU ops), aligned loads.
// SRC=0: raw pts (fallback when workspace can't hold the 8.4MB padded array).
// Round-9 additions vs round-0: distkey4 via precomputed p2 (SRC=1) and per-wave
// ballot-aggregated candidate append (replaces ~330 serialized one-address LDS atomics).
template <int SRC>
__device__ __forceinline__ void group_body(
    const float* __restrict__ pts, const float4* __restrict__ pts4,
    const float4* __restrict__ cent_pad, const float* __restrict__ w1,
    const float* __restrict__ b1, const float* __restrict__ w2t,
    const float* __restrict__ b2, const float* __restrict__ lns,
    const float* __restrict__ lnb, float* __restrict__ tok_out) {
    __shared__ __align__(16) union {
        unsigned hist[NBUCK];
        unsigned long long cand[CANDCAP];
    } sh;
    __shared__ int selIdx[KK];
    __shared__ float4 localPt[KK];
    __shared__ float w1s[3 * HH];
    __shared__ float b1s[HH];
    __shared__ __align__(16) float hbar[HH];
    __shared__ float partial[256];
    __shared__ float red2[8];
    __shared__ float toks[DD];
    __shared__ int waveSum[4];
    __shared__ unsigned long long wmin[4];
    __shared__ unsigned TA_S;
    __shared__ int cntS;
    __shared__ unsigned long long lastS;
    __shared__ float muS, rstdS;

    const int tid = threadIdx.x;
    // XCD-aware swizzle: each XCD sees only 4 batches' points -> L2 resident
    int bid = blockIdx.x;
    int xcd = bid & 7, sub = bid >> 3;
    int b = xcd * 4 + (sub >> 7);
    int g = sub & 127;

    const float* p = pts + (size_t)b * NN * 3;
    const float4* p4 = (const float4*)p;
    const float4* pp = pts4 + (size_t)b * NN;
    float4 c4 = cent_pad[b * GG + g];

    for (int i = tid; i < 3 * HH; i += 256) w1s[i] = w1[i];
    if (tid < HH) b1s[tid] = b1[tid];
    for (int i = tid; i < NBUCK; i += 256) sh.hist[i] = 0;
    if (tid == 0) cntS = 0;
    __syncthreads();

    const int lane = tid & 63, wid = tid >> 6;

    // ---- pass 1: histogram of 11-bit key prefixes
    for (int i = 0; i < 16; i++) {
        int t4 = i * 256 + tid;
        unsigned k0, k1, k2, k3;
        if (SRC) {
            int nb = 4 * t4;
            k0 = distkey4(pp[nb + 0], c4);
            k1 = distkey4(pp[nb + 1], c4);
            k2 = distkey4(pp[nb + 2], c4);
            k3 = distkey4(pp[nb + 3], c4);
        } else {
            float4 A = p4[3 * t4], B = p4[3 * t4 + 1], C = p4[3 * t4 + 2];
            k0 = distkey(A.x, A.y, A.z, c4);
            k1 = distkey(A.w, B.x, B.y, c4);
            k2 = distkey(B.z, B.w, C.x, c4);
            k3 = distkey(C.y, C.z, C.w, c4);
        }
        atomicAdd(&sh.hist[k0 >> 21], 1u);
        atomicAdd(&sh.hist[k1 >> 21], 1u);
        atomicAdd(&sh.hist[k2 >> 21], 1u);
        atomicAdd(&sh.hist[k3 >> 21], 1u);
    }
    __syncthreads();

    // ---- boundary bucket: smallest T with cumcount(<=T) >= 64
    {
        uint4 h0 = ((const uint4*)sh.hist)[tid * 2];
        uint4 h1 = ((const uint4*)sh.hist)[tid * 2 + 1];
        int loc[8] = {(int)h0.x, (int)h0.y, (int)h0.z, (int)h0.w,
                      (int)h1.x, (int)h1.y, (int)h1.z, (int)h1.w};
        int s = 0;
#pragma unroll
        for (int j = 0; j < 8; j++) s += loc[j];
        int v = s;
#pragma unroll
        for (int off = 1; off < 64; off <<= 1) {
            int o = __shfl_up(v, off);
            if (lane >= off) v += o;
        }
        if (lane == 63) waveSum[wid] = v;
        __syncthreads();
        int base = 0;
        for (int w = 0; w < wid; w++) base += waveSum[w];
        int c = base + v - s;
#pragma unroll
        for (int j = 0; j < 8; j++) {
            if (c < KK && c + loc[j] >= KK) TA_S = (unsigned)(tid * 8 + j);
            c += loc[j];
        }
        __syncthreads();
    }
    unsigned TA = TA_S;

    // ---- pass 2: collect candidates in buckets <= TA; per-wave ballot aggregation
    for (int i = 0; i < 16; i++) {
        int t4 = i * 256 + tid;
        unsigned k[4];
        if (SRC) {
            int nb = 4 * t4;
            k[0] = distkey4(pp[nb + 0], c4);
            k[1] = distkey4(pp[nb + 1], c4);
            k[2] = distkey4(pp[nb + 2], c4);
            k[3] = distkey4(pp[nb + 3], c4);
        } else {
            float4 A = p4[3 * t4], B = p4[3 * t4 + 1], C = p4[3 * t4 + 2];
            k[0] = distkey(A.x, A.y, A.z, c4);
            k[1] = distkey(A.w, B.x, B.y, c4);
            k[2] = distkey(B.z, B.w, C.x, c4);
            k[3] = distkey(C.y, C.z, C.w, c4);
        }
#pragma unroll
        for (int q = 0; q < 4; q++) {
            bool take = (k[q] >> 21) <= TA;
            unsigned long long m = __ballot(take);
            if (m != 0ull) {
                int cw = __popcll(m);
                int base = 0;
                if (lane == 0) base = atomicAdd(&cntS, cw);
                base = __shfl(base, 0);
                if (take) {
                    int pos = base + __popcll(m & ((1ull << lane) - 1ull));
                    if (pos < CANDCAP)
                        sh.cand[pos] =
                            ((unsigned long long)k[q] << 32) | (unsigned)(4 * t4 + q);
                }
            }
        }
    }
    __syncthreads();
    int cnt = cntS;  // >= 64 by construction

    if (cnt <= CANDCAP) {
        // ---- exact rank-select of the 64 lexicographically smallest (key,idx)
        for (int c0 = tid; c0 < cnt; c0 += 256) {
            unsigned long long pr = sh.cand[c0];
            int rank = 0;
            int j = 0;
            for (; j + 8 <= cnt; j += 8) {
                unsigned long long a0 = sh.cand[j + 0];
                unsigned long long a1 = sh.cand[j + 1];
                unsigned long long a2 = sh.cand[j + 2];
                unsigned long long a3 = sh.cand[j + 3];
                unsigned long long a4 = sh.cand[j + 4];
                unsigned long long a5 = sh.cand[j + 5];
                unsigned long long a6 = sh.cand[j + 6];
                unsigned long long a7 = sh.cand[j + 7];
                rank += (int)(a0 < pr) + (int)(a1 < pr) + (int)(a2 < pr) +
                        (int)(a3 < pr) + (int)(a4 < pr) + (int)(a5 < pr) +
                        (int)(a6 < pr) + (int)(a7 < pr);
            }
            for (; j < cnt; j++) rank += (int)(sh.cand[j] < pr);
            if (rank < KK) selIdx[rank] = (int)(unsigned)pr;
        }
        __syncthreads();
    } else {
        // ---- pathological fallback (never triggers on real data): exact 64-round
        // min-extraction, keys recomputed each round
        if (tid == 0) lastS = 0ull;
        __syncthreads();
        for (int r = 0; r < KK; r++) {
            unsigned long long last = lastS;
            unsigned long long best = 0xFFFFFFFFFFFFFFFFull;
            for (int i = 0; i < 16; i++) {
                int t4 = i * 256 + tid;
                unsigned k[4];
                if (SRC) {
                    int nb = 4 * t4;
                    k[0] = distkey4(pp[nb + 0], c4);
                    k[1] = distkey4(pp[nb + 1], c4);
                    k[2] = distkey4(pp[nb + 2], c4);
                    k[3] = distkey4(pp[nb + 3], c4);
                } else {
                    float4 A = p4[3 * t4], B = p4[3 * t4 + 1], C = p4[3 * t4 + 2];
                    k[0] = distkey(A.x, A.y, A.z, c4);
                    k[1] = distkey(A.w, B.x, B.y, c4);
                    k[2] = distkey(B.z, B.w, C.x, c4);
                    k[3] = distkey(C.y, C.z, C.w, c4);
                }
#pragma unroll
                for (int q = 0; q < 4; q++) {
                    unsigned long long pr =
                        ((unsigned long long)k[q] << 32) | (unsigned)(4 * t4 + q);
                    if ((r == 0 || pr > last) && pr < best) best = pr;
                }
            }
            unsigned blo = (unsigned)best, bhi = (unsigned)(best >> 32);
#pragma unroll
            for (int off = 32; off >= 1; off >>= 1) {
                unsigned olo = __shfl_down(blo, off);
                unsigned ohi = __shfl_down(bhi, off);
                unsigned long long ob = ((unsigned long long)ohi << 32) | olo;
                unsigned long long cur = ((unsigned long long)bhi << 32) | blo;
                if (ob < cur) { blo = olo; bhi = ohi; }
            }
            if (lane == 0) wmin[wid] = ((unsigned long long)bhi << 32) | blo;
            __syncthreads();
            if (tid == 0) {
                unsigned long long m = wmin[0];
                for (int w = 1; w < 4; w++) if (wmin[w] < m) m = wmin[w];
                selIdx[r] = (int)(unsigned)m;
                lastS = m;
            }
            __syncthreads();
        }
    }

    // ---- gather + local coords
    if (tid < KK) {
        int n = selIdx[tid];
        float px, py, pz;
        if (SRC) {
            float4 v = pp[n];
            px = v.x; py = v.y; pz = v.z;
        } else {
            px = p[n * 3]; py = p[n * 3 + 1]; pz = p[n * 3 + 2];
        }
        localPt[tid] = make_float4(px - c4.x, py - c4.y, pz - c4.z, 0.f);
    }
    __syncthreads();
    // ---- layer1 + exact GELU + mean over K (2 threads per feature, 32 pts each)
    {
        int f = tid & 127, half = tid >> 7;
        float wa = w1s[f], wb = w1s[HH + f], wc = w1s[2 * HH + f], bb = b1s[f];
        float s = 0.f;
        for (int k = half * 32; k < half * 32 + 32; k++) {
            float4 lp = localPt[k];
            float a = lp.x * wa + lp.y * wb + lp.z * wc + bb;
            float hh = 0.5f * a * (1.0f + erff(a * 0.70710678118654752440f));
            s += hh;
        }
        partial[tid] = s;
    }
    __syncthreads();
    if (tid < HH) hbar[tid] = (partial[tid] + partial[tid + HH]) * (1.0f / 64.0f);
    __syncthreads();
    // ---- layer2: tokens = hbar @ w2 + b2   (mean commutes with the linear layer)
    for (int f2 = tid; f2 < DD; f2 += 256) {
        const float4* wrow = (const float4*)(w2t + f2 * HH);
        const float4* hb = (const float4*)hbar;
        float acc = b2[f2];
#pragma unroll 8
        for (int q = 0; q < 32; q++) {
            float4 w4 = wrow[q];
            float4 h4 = hb[q];
            acc += h4.x * w4.x + h4.y * w4.y + h4.z * w4.z + h4.w * w4.w;
        }
        toks[f2] = acc;
    }
    __syncthreads();
    // ---- LayerNorm over 384
    {
        float s1 = 0.f, s2 = 0.f;
        for (int f2 = tid; f2 < DD; f2 += 256) {
            float v = toks[f2];
            s1 += v;
            s2 += v * v;
        }
#pragma unroll
        for (int off = 32; off >= 1; off >>= 1) {
            s1 += __shfl_down(s1, off);
            s2 += __shfl_down(s2, off);
        }
        if (lane == 0) { partial[wid] = s1; red2[wid] = s2; }
        __syncthreads();
        if (tid == 0) {
            float t1 = partial[0] + partial[1] + partial[2] + partial[3];
            float t2 = red2[0] + red2[1] + red2[2] + red2[3];
            float mu = t1 / (float)DD;
            float var = t2 / (float)DD - mu * mu;
            muS = mu;
            rstdS = rsqrtf(var + LN_EPS);
        }
        __syncthreads();
    }
    float mu = muS, rstd = rstdS;
    float* outp = tok_out + ((size_t)b * GG + g) * DD;
    for (int f2 = tid; f2 < DD; f2 += 256) {
        outp[f2] = (toks[f2] - mu) * rstd * lns[f2] + lnb[f2];
    }
}

__global__ __launch_bounds__(256, 6) void group_kernel_v2(
    const float* __restrict__ pts, const float4* __restrict__ pts4,
    const float4* __restrict__ cent_pad, const float* __restrict__ w1,
    const float* __restrict__ b1, const float* __restrict__ w2t,
    const float* __restrict__ b2, const float* __restrict__ lns,
    const float* __restrict__ lnb, float* __restrict__ tok_out) {
    group_body<1>(pts, pts4, cent_pad, w1, b1, w2t, b2, lns, lnb, tok_out);
}

__global__ __launch_bounds__(256, 6) void group_kernel_v1(
    const float* __restrict__ pts, const float4* __restrict__ cent_pad,
    const float* __restrict__ w1, const float* __restrict__ b1,
    const float* __restrict__ w2t, const float* __restrict__ b2,
    const float* __restrict__ lns, const float* __restrict__ lnb,
    float* __restrict__ tok_out) {
    group_body<0>(pts, (const float4*)pts, cent_pad, w1, b1, w2t, b2, lns, lnb,
                  tok_out);
}

extern "C" void kernel_launch(void* const* d_in, const int* in_sizes, int n_in,
                              void* d_out, int out_size, void* d_ws, size_t ws_size,
                              hipStream_t stream) {
    const float* pts = (const float*)d_in[0];
    const float* w1 = (const float*)d_in[1];
    const float* b1 = (const float*)d_in[2];
    const float* w2 = (const float*)d_in[3];
    const float* b2 = (const float*)d_in[4];
    const float* lns = (const float*)d_in[5];
    const float* lnb = (const float*)d_in[6];
    float* out = (float*)d_out;

    // ws layout: cent_pad [B*G float4] @0 (64KB), w2t [384*128 f32] @64KB (192KB),
    //            pts4 [B*N float4] @256KB (8.4MB, only if ws_size allows)
    float4* cent_pad = (float4*)d_ws;
    float* w2t = (float*)((char*)d_ws + 64 * 1024);
    float4* pts4 = (float4*)((char*)d_ws + 256 * 1024);
    size_t need = 256 * 1024 + (size_t)BB * NN * sizeof(float4);

    prep_kernel<<<192, 256, 0, stream>>>(w2, w2t);
    if (ws_size >= need) {
        prep_pts4<<<(BB * NN / 4) / 256, 256, 0, stream>>>(pts, pts4);
        fps_kernel<<<BB, 512, 0, stream>>>(pts, out, cent_pad);
        group_kernel_v2<<<BB * GG, 256, 0, stream>>>(pts, pts4, cent_pad, w1, b1, w2t,
                                                     b2, lns, lnb, out + BB * GG * 3);
    } else {
        fps_kernel<<<BB, 512, 0, stream>>>(pts, out, cent_pad);
        group_kernel_v1<<<BB * GG, 256, 0, stream>>>(pts, cent_pad, w1, b1, w2t, b2,
                                                     lns, lnb, out + BB * GG * 3);
    }
}